// Round 10
// baseline (1155.926 us; speedup 1.0000x reference)
//
#include <hip/hip_runtime.h>
#include <hip/hip_bf16.h>

#define NTOK 49
#define DIM 384
#define HEADS 12
#define SCALE 0.17677669529663687f

typedef __attribute__((ext_vector_type(8))) short bf16x8;
typedef __attribute__((ext_vector_type(4))) float f32x4;

#define MFMA16(a, b, c) __builtin_amdgcn_mfma_f32_16x16x32_bf16((a), (b), (c), 0, 0, 0)

__device__ __forceinline__ short f2bf(float f) {
  __hip_bfloat16 h = __float2bfloat16(f);
  return __builtin_bit_cast(short, h);
}

// Full-K=32 fragment from two K=16 C-tile slices (same relabel on A and B -> exact).
__device__ __forceinline__ bf16x8 pack8(f32x4 a, f32x4 b) {
  bf16x8 r;
#pragma unroll
  for (int i = 0; i < 4; ++i) { r[i] = f2bf(a[i]); r[i + 4] = f2bf(b[i]); }
  return r;
}

// ws layout:
//   wqT  : short [384][384]   elem off 0        (Wq^T row-major [n][k])
//   wkvT : short [768][384]   elem off 147456   (rows 0-383 K, 384-767 V)
//   wpT  : short [384][384]   elem off 442368
//   biasq: float [12][49][52] byte off 1179648
#define WQT_OFF   0
#define WKVT_OFF  147456
#define WPT_OFF   442368
#define BIAS_BYTE_OFF 1179648
#define BIAS_RL   52

__global__ void prep_kernel(const float* __restrict__ qw, const float* __restrict__ kvw,
                            const float* __restrict__ pw, const float* __restrict__ bt,
                            short* __restrict__ wsS, float* __restrict__ biasq) {
  int id = blockIdx.x * 256 + threadIdx.x;
  const int SZ1 = 384 * 384;
  const int SZ2 = 768 * 384;
  const int SZ3 = 384 * 384;
  if (id < SZ1) {
    int n = id / 384, k = id % 384;
    wsS[WQT_OFF + id] = f2bf(qw[k * 384 + n]);
  } else if (id < SZ1 + SZ2) {
    int t = id - SZ1; int n = t / 384, k = t % 384;
    wsS[WKVT_OFF + t] = f2bf(kvw[k * 768 + n]);
  } else if (id < SZ1 + SZ2 + SZ3) {
    int t = id - (SZ1 + SZ2); int n = t / 384, k = t % 384;
    wsS[WPT_OFF + t] = f2bf(pw[k * 384 + n]);
  } else if (id < SZ1 + SZ2 + SZ3 + HEADS * NTOK * BIAS_RL) {
    int t = id - (SZ1 + SZ2 + SZ3);
    int h = t / (NTOK * BIAS_RL); int rc = t % (NTOK * BIAS_RL);
    int q = rc / BIAS_RL, c = rc % BIAS_RL;
    float v = 0.0f;
    if (c < NTOK) {
      int idx = ((q / 7 - c / 7) + 6) * 13 + ((q % 7 - c % 7) + 6);
      v = bt[idx * HEADS + h];
    }
    biasq[t] = v;
  }
}

// LDS (shorts). Row stride 392 shorts = 196 dw == 4 mod 32: 16-row b128 frag
// reads land 2 lanes/bank (free).
#define X_OFF    0            // [49][392]  x_body
#define XE_OFF   19208        // [49][392]  x_edge; reused as OALL after Q phase
#define LDS_ELEMS 38416
#define LDS_BYTES (LDS_ELEMS * 2)   // 76832 B

// 1024 thr = 16 waves = 4 waves/SIMD co-resident BY CONSTRUCTION (no scheduler
// packing needed). (1024,1) implies VGPR cap 512/4 = 128, which hipcc honors
// (caps <=128 honored exactly; >128 falls back to ~84 heuristic — R2-R9).
__global__ __launch_bounds__(1024, 1)
void fused_kernel(const float* __restrict__ xe, const float* __restrict__ xb,
                  const float* __restrict__ qb, const float* __restrict__ kvb,
                  const float* __restrict__ pb,
                  const short* __restrict__ wqT, const short* __restrict__ wkvT,
                  const short* __restrict__ wpT, const float* __restrict__ biasq,
                  float* __restrict__ out) {
  extern __shared__ short lds[];
  short* X    = lds + X_OFF;     // x_body
  short* XE   = lds + XE_OFF;    // x_edge
  short* OALL = XE;              // O tiles after Q phase (XE dead)

  const int b   = blockIdx.x;
  const int tid = threadIdx.x;
  const int u   = tid >> 6;      // wave 0..15; waves 0..11 own head u
  const int l   = tid & 63;
  const int m16 = l & 15;
  const int g   = l >> 4;

  const f32x4 zf = {0.f, 0.f, 0.f, 0.f};

  // ---- stage x_edge -> XE and x_body -> X (bf16, 8B packed writes) ----
  const float* xew = xe + (size_t)b * (NTOK * DIM);
  const float* xbw = xb + (size_t)b * (NTOK * DIM);
  for (int i4 = tid; i4 < 2 * (NTOK * DIM / 4); i4 += 1024) {
    int eb = i4 < (NTOK * DIM / 4);
    int e = (eb ? i4 : i4 - NTOK * DIM / 4) * 4;
    const float* src = eb ? xew : xbw;
    short* dst = eb ? XE : X;
    int r = e / DIM, c = e % DIM;
    float4 v = *(const float4*)(src + e);
    ushort4 s;
    s.x = (unsigned short)f2bf(v.x); s.y = (unsigned short)f2bf(v.y);
    s.z = (unsigned short)f2bf(v.z); s.w = (unsigned short)f2bf(v.w);
    *(ushort4*)&dst[r * 392 + c] = s;
  }
  __syncthreads();   // [#1]

  bf16x8 qfr[4];
  const int h = u;   // head for waves 0..11

  // ================= Q^T GEMM (wave-private, head u) ============
  if (u < 12) {
    f32x4 qc[2][4];
#pragma unroll
    for (int dt = 0; dt < 2; ++dt)
#pragma unroll
      for (int tb = 0; tb < 4; ++tb) qc[dt][tb] = zf;

#pragma unroll 2
    for (int kk = 0; kk < 12; ++kk) {
      const int ko = kk * 32 + g * 8;
      bf16x8 xv[4];
#pragma unroll
      for (int tb = 0; tb < 4; ++tb) {
        int tr = tb * 16 + m16; tr = tr < 49 ? tr : 48;
        xv[tb] = *(const bf16x8*)(&XE[tr * 392 + ko]);
      }
#pragma unroll
      for (int dt = 0; dt < 2; ++dt) {
        bf16x8 aw = *(const bf16x8*)(wqT + (size_t)(h * 32 + dt * 16 + m16) * 384 + ko);
#pragma unroll
        for (int tb = 0; tb < 4; ++tb) qc[dt][tb] = MFMA16(aw, xv[tb], qc[dt][tb]);
      }
    }
    float4 t0 = *(const float4*)(qb + h * 32 + g * 4);
    float4 t1 = *(const float4*)(qb + h * 32 + 16 + g * 4);
    f32x4 b0 = {t0.x, t0.y, t0.z, t0.w};
    f32x4 b1 = {t1.x, t1.y, t1.z, t1.w};
#pragma unroll
    for (int qt = 0; qt < 4; ++qt)
      qfr[qt] = pack8((qc[0][qt] + b0) * SCALE, (qc[1][qt] + b1) * SCALE);
  }
  __syncthreads();   // [#2] all XE reads done -> XE becomes OALL

  // ================= fused K+V GEMM + attention (wave-private) ==============
  if (u < 12) {
    f32x4 kc[2][4], vc[4][2];
#pragma unroll
    for (int dt = 0; dt < 2; ++dt)
#pragma unroll
      for (int tb = 0; tb < 4; ++tb) kc[dt][tb] = zf;
#pragma unroll
    for (int tb = 0; tb < 4; ++tb)
#pragma unroll
      for (int db = 0; db < 2; ++db) vc[tb][db] = zf;

#pragma unroll 1
    for (int kk = 0; kk < 12; ++kk) {
      const int ko = kk * 32 + g * 8;
      bf16x8 xv[4];
#pragma unroll
      for (int tb = 0; tb < 4; ++tb) {
        int tr = tb * 16 + m16; tr = tr < 49 ? tr : 48;
        xv[tb] = *(const bf16x8*)(&X[tr * 392 + ko]);
      }
      bf16x8 kw[2], vw[2];
#pragma unroll
      for (int dt = 0; dt < 2; ++dt)
        kw[dt] = *(const bf16x8*)(wkvT + (size_t)(h * 32 + dt * 16 + m16) * 384 + ko);
#pragma unroll
      for (int db = 0; db < 2; ++db)
        vw[db] = *(const bf16x8*)(wkvT + (size_t)(384 + h * 32 + db * 16 + m16) * 384 + ko);
#pragma unroll
      for (int dt = 0; dt < 2; ++dt)
#pragma unroll
        for (int tb = 0; tb < 4; ++tb) kc[dt][tb] = MFMA16(kw[dt], xv[tb], kc[dt][tb]);
#pragma unroll
      for (int tb = 0; tb < 4; ++tb)
#pragma unroll
        for (int db = 0; db < 2; ++db) vc[tb][db] = MFMA16(xv[tb], vw[db], vc[tb][db]);
    }
    bf16x8 kfr[4], vfr[2][2];
    {
      float4 t0 = *(const float4*)(kvb + h * 32 + g * 4);
      float4 t1 = *(const float4*)(kvb + h * 32 + 16 + g * 4);
      f32x4 b0 = {t0.x, t0.y, t0.z, t0.w};
      f32x4 b1 = {t1.x, t1.y, t1.z, t1.w};
#pragma unroll
      for (int tb = 0; tb < 4; ++tb) kfr[tb] = pack8(kc[0][tb] + b0, kc[1][tb] + b1);
    }
#pragma unroll
    for (int db = 0; db < 2; ++db) {
      float vbv = kvb[384 + h * 32 + db * 16 + m16];
      f32x4 bv = {vbv, vbv, vbv, vbv};
#pragma unroll
      for (int t = 0; t < 2; ++t)
        vfr[t][db] = pack8(vc[2 * t][db] + bv, vc[2 * t + 1][db] + bv);
    }

    // ---- attention per q-tile: S (1 MFMA/k-tile), softmax, PV ----
#pragma unroll
    for (int qt = 0; qt < 4; ++qt) {
      int q = qt * 16 + m16; int qcl = q < 49 ? q : 48;
      const float* bq = biasq + (size_t)(h * NTOK + qcl) * BIAS_RL;
      f32x4 s[4];
#pragma unroll
      for (int tb = 0; tb < 4; ++tb) s[tb] = MFMA16(kfr[tb], qfr[qt], zf);

      float sv[4][4];
      float mx = -3.0e38f;
#pragma unroll
      for (int tb = 0; tb < 4; ++tb) {
        int k0 = tb * 16 + g * 4;
        int kcl = k0 <= 48 ? k0 : 48;     // bias row padded to 52
        float4 bv = *(const float4*)(bq + kcl);
        sv[tb][0] = (k0 + 0 < 49) ? s[tb][0] + bv.x : -3.0e38f;
        sv[tb][1] = (k0 + 1 < 49) ? s[tb][1] + bv.y : -3.0e38f;
        sv[tb][2] = (k0 + 2 < 49) ? s[tb][2] + bv.z : -3.0e38f;
        sv[tb][3] = (k0 + 3 < 49) ? s[tb][3] + bv.w : -3.0e38f;
        mx = fmaxf(mx, fmaxf(fmaxf(sv[tb][0], sv[tb][1]), fmaxf(sv[tb][2], sv[tb][3])));
      }
      mx = fmaxf(mx, __shfl_xor(mx, 16));
      mx = fmaxf(mx, __shfl_xor(mx, 32));
      float sum = 0.f;
#pragma unroll
      for (int tb = 0; tb < 4; ++tb)
#pragma unroll
        for (int i = 0; i < 4; ++i) {
          float e = __expf(sv[tb][i] - mx);
          sv[tb][i] = e;
          sum += e;
        }
      sum += __shfl_xor(sum, 16);
      sum += __shfl_xor(sum, 32);
      float inv = 1.0f / sum;

      bf16x8 pfr[2];
#pragma unroll
      for (int t = 0; t < 2; ++t) {
        f32x4 lo = {sv[2 * t][0] * inv, sv[2 * t][1] * inv, sv[2 * t][2] * inv, sv[2 * t][3] * inv};
        f32x4 hi = {sv[2 * t + 1][0] * inv, sv[2 * t + 1][1] * inv, sv[2 * t + 1][2] * inv, sv[2 * t + 1][3] * inv};
        pfr[t] = pack8(lo, hi);
      }
      f32x4 o0 = zf, o1 = zf;
      o0 = MFMA16(pfr[0], vfr[0][0], o0); o0 = MFMA16(pfr[1], vfr[1][0], o0);
      o1 = MFMA16(pfr[0], vfr[0][1], o1); o1 = MFMA16(pfr[1], vfr[1][1], o1);
#pragma unroll
      for (int i = 0; i < 4; ++i) {
        int r = qt * 16 + g * 4 + i;
        if (r < 49) {
          OALL[r * 392 + h * 32 + m16]      = f2bf(o0[i]);
          OALL[r * 392 + h * 32 + 16 + m16] = f2bf(o1[i]);
        }
      }
    }
  }
  __syncthreads();   // [#3] OALL complete

  // ====== out-projection: 16 waves, wave (qg,cg) = 1 q-tile x 6 col-tiles ===
  {
    const int qg = u >> 2;        // q-tile 0..3
    const int cg = u & 3;         // col-group 0..3 (6 tiles each)
    f32x4 pacc[6];
#pragma unroll
    for (int c = 0; c < 6; ++c) pacc[c] = zf;
#pragma unroll 2
    for (int kk = 0; kk < 12; ++kk) {
      const int ko = kk * 32 + g * 8;
      int r = qg * 16 + m16; r = r < 49 ? r : 48;
      bf16x8 af = *(const bf16x8*)(&OALL[r * 392 + ko]);
#pragma unroll
      for (int c = 0; c < 6; ++c) {
        bf16x8 bw = *(const bf16x8*)(wpT + (size_t)((cg * 6 + c) * 16 + m16) * 384 + ko);
        pacc[c] = MFMA16(af, bw, pacc[c]);
      }
    }
    float* outw = out + (size_t)b * (NTOK * DIM);
#pragma unroll
    for (int c = 0; c < 6; ++c) {
      int col = (cg * 6 + c) * 16 + m16;
      float pbv = pb[col];
#pragma unroll
      for (int i = 0; i < 4; ++i) {
        int r = qg * 16 + g * 4 + i;
        if (r < 49) outw[r * DIM + col] = pacc[c][i] + pbv;
      }
    }
  }
}

extern "C" void kernel_launch(void* const* d_in, const int* in_sizes, int n_in,
                              void* d_out, int out_size, void* d_ws, size_t ws_size,
                              hipStream_t stream) {
  const float* xe  = (const float*)d_in[0];
  const float* xb  = (const float*)d_in[1];
  const float* qw  = (const float*)d_in[2];
  const float* qb  = (const float*)d_in[3];
  const float* kvw = (const float*)d_in[4];
  const float* kvb = (const float*)d_in[5];
  const float* pw  = (const float*)d_in[6];
  const float* pb  = (const float*)d_in[7];
  const float* bt  = (const float*)d_in[8];
  float* out = (float*)d_out;
  short* wsS = (short*)d_ws;
  float* biasq = (float*)((char*)d_ws + BIAS_BYTE_OFF);

  const int nwin = in_sizes[0] / (NTOK * DIM);

  const int prep_items = 384 * 384 + 768 * 384 + 384 * 384 + HEADS * NTOK * BIAS_RL;
  prep_kernel<<<(prep_items + 255) / 256, 256, 0, stream>>>(qw, kvw, pw, bt, wsS, biasq);

  hipFuncSetAttribute((const void*)fused_kernel,
                      hipFuncAttributeMaxDynamicSharedMemorySize, LDS_BYTES);
  fused_kernel<<<nwin, 1024, LDS_BYTES, stream>>>(
      xe, xb, qb, kvb, pb,
      wsS + WQT_OFF, wsS + WKVT_OFF, wsS + WPT_OFF, biasq, out);
}

// Round 11
// 950.245 us; speedup vs baseline: 1.2165x; 1.2165x over previous
//
#include <hip/hip_runtime.h>
#include <hip/hip_bf16.h>

#define NTOK 49
#define DIM 384
#define HEADS 12
#define SCALE 0.17677669529663687f

typedef __attribute__((ext_vector_type(8))) short bf16x8;
typedef __attribute__((ext_vector_type(4))) float f32x4;

#define MFMA16(a, b, c) __builtin_amdgcn_mfma_f32_16x16x32_bf16((a), (b), (c), 0, 0, 0)

__device__ __forceinline__ short f2bf(float f) {
  __hip_bfloat16 h = __float2bfloat16(f);
  return __builtin_bit_cast(short, h);
}

// Full-K=32 fragment from two K=16 C-tile slices (same relabel on A and B -> exact).
__device__ __forceinline__ bf16x8 pack8(f32x4 a, f32x4 b) {
  bf16x8 r;
#pragma unroll
  for (int i = 0; i < 4; ++i) { r[i] = f2bf(a[i]); r[i + 4] = f2bf(b[i]); }
  return r;
}

// ws layout:
//   wqT  : short [384][384]   elem off 0        (Wq^T row-major [n][k])
//   wkvT : short [768][384]   elem off 147456   (rows 0-383 K, 384-767 V)
//   wpT  : short [384][384]   elem off 442368
//   biasf: float [12][4][4][64][4] byte off 1179648  (fragment-ordered, coalesced)
#define WQT_OFF   0
#define WKVT_OFF  147456
#define WPT_OFF   442368
#define BIAS_BYTE_OFF 1179648
#define BIAS_ITEMS (12 * 4 * 4 * 64 * 4)

__global__ void prep_kernel(const float* __restrict__ qw, const float* __restrict__ kvw,
                            const float* __restrict__ pw, const float* __restrict__ bt,
                            short* __restrict__ wsS, float* __restrict__ biasf) {
  int id = blockIdx.x * 256 + threadIdx.x;
  const int SZ1 = 384 * 384;
  const int SZ2 = 768 * 384;
  const int SZ3 = 384 * 384;
  if (id < SZ1) {
    int n = id / 384, k = id % 384;
    wsS[WQT_OFF + id] = f2bf(qw[k * 384 + n]);
  } else if (id < SZ1 + SZ2) {
    int t = id - SZ1; int n = t / 384, k = t % 384;
    wsS[WKVT_OFF + t] = f2bf(kvw[k * 768 + n]);
  } else if (id < SZ1 + SZ2 + SZ3) {
    int t = id - (SZ1 + SZ2); int n = t / 384, k = t % 384;
    wsS[WPT_OFF + t] = f2bf(pw[k * 384 + n]);
  } else if (id < SZ1 + SZ2 + SZ3 + BIAS_ITEMS) {
    int t = id - (SZ1 + SZ2 + SZ3);
    // [h][qt][tb][l][i]: lane l of fragment (qt,tb) element i
    int i  = t & 3;
    int lm = (t >> 2) & 63;
    int tb = (t >> 8) & 3;
    int qt = (t >> 10) & 3;
    int h  = t >> 12;
    int q = qt * 16 + (lm & 15);
    int k = tb * 16 + (lm >> 4) * 4 + i;
    float v = 0.0f;
    if (q < NTOK && k < NTOK) {
      int idx = ((q / 7 - k / 7) + 6) * 13 + ((q % 7 - k % 7) + 6);
      v = bt[idx * HEADS + h];
    }
    biasf[t] = v;
  }
}

// LDS (shorts). Row stride 392 shorts = 196 dw == 4 mod 32: 16-row b128 frag
// reads land 2 lanes/bank (free).
#define X_OFF    0            // [49][392]  x_body
#define XE_OFF   19208        // [49][392]  x_edge; reused as OALL after barrier #2
#define LDS_ELEMS 38416
#define LDS_BYTES (LDS_ELEMS * 2)   // 76832 B

__global__ __launch_bounds__(1024, 1)
void fused_kernel(const float* __restrict__ xe, const float* __restrict__ xb,
                  const float* __restrict__ qb, const float* __restrict__ kvb,
                  const float* __restrict__ pb,
                  const short* __restrict__ wqT, const short* __restrict__ wkvT,
                  const short* __restrict__ wpT, const float* __restrict__ biasf,
                  float* __restrict__ out) {
  extern __shared__ short lds[];
  short* X    = lds + X_OFF;     // x_body
  short* XE   = lds + XE_OFF;    // x_edge
  short* OALL = XE;              // O tiles after barrier #2

  const int b   = blockIdx.x;
  const int tid = threadIdx.x;
  const int u   = tid >> 6;      // wave 0..15; waves 0..11 own head u
  const int l   = tid & 63;
  const int m16 = l & 15;
  const int g   = l >> 4;
  const int h   = u;

  const f32x4 zf = {0.f, 0.f, 0.f, 0.f};

  // ---- stage x_edge -> XE and x_body -> X (bf16, 8B packed writes) ----
  const float* xew = xe + (size_t)b * (NTOK * DIM);
  const float* xbw = xb + (size_t)b * (NTOK * DIM);
#pragma unroll 4
  for (int i4 = tid; i4 < 2 * (NTOK * DIM / 4); i4 += 1024) {
    int eb = i4 < (NTOK * DIM / 4);
    int e = (eb ? i4 : i4 - NTOK * DIM / 4) * 4;
    const float* src = eb ? xew : xbw;
    short* dst = eb ? XE : X;
    int r = e / DIM, c = e % DIM;
    float4 v = *(const float4*)(src + e);
    ushort4 s;
    s.x = (unsigned short)f2bf(v.x); s.y = (unsigned short)f2bf(v.y);
    s.z = (unsigned short)f2bf(v.z); s.w = (unsigned short)f2bf(v.w);
    *(ushort4*)&dst[r * 392 + c] = s;
  }
  __syncthreads();   // [#1]

  bf16x8 qfr[4], kfr[4], vfr[2][2];

  if (u < 12) {
    // ================= Q pass (ping-pong weight prefetch) =================
    {
      f32x4 qc[2][4];
#pragma unroll
      for (int dt = 0; dt < 2; ++dt)
#pragma unroll
        for (int tb = 0; tb < 4; ++tb) qc[dt][tb] = zf;
      const short* w0 = wqT + (size_t)(h * 32 + m16) * 384;
      const short* w1 = wqT + (size_t)(h * 32 + 16 + m16) * 384;
      bf16x8 wA0 = *(const bf16x8*)(w0 + g * 8);
      bf16x8 wA1 = *(const bf16x8*)(w1 + g * 8);
#pragma unroll 1
      for (int kk = 0; kk < 12; kk += 2) {
        const int koB = (kk + 1) * 32 + g * 8;
        bf16x8 wB0 = *(const bf16x8*)(w0 + koB);
        bf16x8 wB1 = *(const bf16x8*)(w1 + koB);
        {
          const int ko = kk * 32 + g * 8;
#pragma unroll
          for (int tb = 0; tb < 4; ++tb) {
            int tr = tb * 16 + m16; tr = tr < 49 ? tr : 48;
            bf16x8 xv = *(const bf16x8*)(&XE[tr * 392 + ko]);
            qc[0][tb] = MFMA16(wA0, xv, qc[0][tb]);
            qc[1][tb] = MFMA16(wA1, xv, qc[1][tb]);
          }
        }
        const int koA = ((kk + 2) % 12) * 32 + g * 8;   // wrap: harmless dead load
        wA0 = *(const bf16x8*)(w0 + koA);
        wA1 = *(const bf16x8*)(w1 + koA);
        {
#pragma unroll
          for (int tb = 0; tb < 4; ++tb) {
            int tr = tb * 16 + m16; tr = tr < 49 ? tr : 48;
            bf16x8 xv = *(const bf16x8*)(&XE[tr * 392 + koB]);
            qc[0][tb] = MFMA16(wB0, xv, qc[0][tb]);
            qc[1][tb] = MFMA16(wB1, xv, qc[1][tb]);
          }
        }
      }
      float4 t0 = *(const float4*)(qb + h * 32 + g * 4);
      float4 t1 = *(const float4*)(qb + h * 32 + 16 + g * 4);
      f32x4 b0 = {t0.x, t0.y, t0.z, t0.w};
      f32x4 b1 = {t1.x, t1.y, t1.z, t1.w};
#pragma unroll
      for (int qt = 0; qt < 4; ++qt)
        qfr[qt] = pack8((qc[0][qt] + b0) * SCALE, (qc[1][qt] + b1) * SCALE);
    }

    // ================= K pass (ping-pong) =================
    {
      f32x4 kc[2][4];
#pragma unroll
      for (int dt = 0; dt < 2; ++dt)
#pragma unroll
        for (int tb = 0; tb < 4; ++tb) kc[dt][tb] = zf;
      const short* w0 = wkvT + (size_t)(h * 32 + m16) * 384;
      const short* w1 = wkvT + (size_t)(h * 32 + 16 + m16) * 384;
      bf16x8 wA0 = *(const bf16x8*)(w0 + g * 8);
      bf16x8 wA1 = *(const bf16x8*)(w1 + g * 8);
#pragma unroll 1
      for (int kk = 0; kk < 12; kk += 2) {
        const int koB = (kk + 1) * 32 + g * 8;
        bf16x8 wB0 = *(const bf16x8*)(w0 + koB);
        bf16x8 wB1 = *(const bf16x8*)(w1 + koB);
        {
          const int ko = kk * 32 + g * 8;
#pragma unroll
          for (int tb = 0; tb < 4; ++tb) {
            int tr = tb * 16 + m16; tr = tr < 49 ? tr : 48;
            bf16x8 xv = *(const bf16x8*)(&X[tr * 392 + ko]);
            kc[0][tb] = MFMA16(wA0, xv, kc[0][tb]);
            kc[1][tb] = MFMA16(wA1, xv, kc[1][tb]);
          }
        }
        const int koA = ((kk + 2) % 12) * 32 + g * 8;
        wA0 = *(const bf16x8*)(w0 + koA);
        wA1 = *(const bf16x8*)(w1 + koA);
        {
#pragma unroll
          for (int tb = 0; tb < 4; ++tb) {
            int tr = tb * 16 + m16; tr = tr < 49 ? tr : 48;
            bf16x8 xv = *(const bf16x8*)(&X[tr * 392 + koB]);
            kc[0][tb] = MFMA16(wB0, xv, kc[0][tb]);
            kc[1][tb] = MFMA16(wB1, xv, kc[1][tb]);
          }
        }
      }
      float4 t0 = *(const float4*)(kvb + h * 32 + g * 4);
      float4 t1 = *(const float4*)(kvb + h * 32 + 16 + g * 4);
      f32x4 b0 = {t0.x, t0.y, t0.z, t0.w};
      f32x4 b1 = {t1.x, t1.y, t1.z, t1.w};
#pragma unroll
      for (int tb = 0; tb < 4; ++tb) kfr[tb] = pack8(kc[0][tb] + b0, kc[1][tb] + b1);
    }

    // ================= V pass (ping-pong) =================
    {
      f32x4 vc[4][2];
#pragma unroll
      for (int tb = 0; tb < 4; ++tb)
#pragma unroll
        for (int db = 0; db < 2; ++db) vc[tb][db] = zf;
      const short* w0 = wkvT + (size_t)(384 + h * 32 + m16) * 384;
      const short* w1 = wkvT + (size_t)(384 + h * 32 + 16 + m16) * 384;
      bf16x8 wA0 = *(const bf16x8*)(w0 + g * 8);
      bf16x8 wA1 = *(const bf16x8*)(w1 + g * 8);
#pragma unroll 1
      for (int kk = 0; kk < 12; kk += 2) {
        const int koB = (kk + 1) * 32 + g * 8;
        bf16x8 wB0 = *(const bf16x8*)(w0 + koB);
        bf16x8 wB1 = *(const bf16x8*)(w1 + koB);
        {
          const int ko = kk * 32 + g * 8;
#pragma unroll
          for (int tb = 0; tb < 4; ++tb) {
            int tr = tb * 16 + m16; tr = tr < 49 ? tr : 48;
            bf16x8 xv = *(const bf16x8*)(&X[tr * 392 + ko]);
            vc[tb][0] = MFMA16(xv, wA0, vc[tb][0]);
            vc[tb][1] = MFMA16(xv, wA1, vc[tb][1]);
          }
        }
        const int koA = ((kk + 2) % 12) * 32 + g * 8;
        wA0 = *(const bf16x8*)(w0 + koA);
        wA1 = *(const bf16x8*)(w1 + koA);
        {
#pragma unroll
          for (int tb = 0; tb < 4; ++tb) {
            int tr = tb * 16 + m16; tr = tr < 49 ? tr : 48;
            bf16x8 xv = *(const bf16x8*)(&X[tr * 392 + koB]);
            vc[tb][0] = MFMA16(xv, wB0, vc[tb][0]);
            vc[tb][1] = MFMA16(xv, wB1, vc[tb][1]);
          }
        }
      }
#pragma unroll
      for (int db = 0; db < 2; ++db) {
        float vbv = kvb[384 + h * 32 + db * 16 + m16];
        f32x4 bv = {vbv, vbv, vbv, vbv};
#pragma unroll
        for (int t = 0; t < 2; ++t)
          vfr[t][db] = pack8(vc[2 * t][db] + bv, vc[2 * t + 1][db] + bv);
      }
    }
  }
  __syncthreads();   // [#2] all XE reads done -> XE becomes OALL

  // ================= attention per q-tile (wave-private) =================
  if (u < 12) {
    const float4* bfh = (const float4*)biasf + (size_t)h * 4 * 4 * 64;
#pragma unroll
    for (int qt = 0; qt < 4; ++qt) {
      const float4* bq = bfh + qt * 4 * 64;
      float4 c0 = bq[l], c1 = bq[64 + l], c2 = bq[128 + l], c3 = bq[192 + l];
      f32x4 B0 = {c0.x, c0.y, c0.z, c0.w};
      f32x4 B1 = {c1.x, c1.y, c1.z, c1.w};
      f32x4 B2 = {c2.x, c2.y, c2.z, c2.w};
      f32x4 B3 = {c3.x, c3.y, c3.z, c3.w};
      f32x4 s[4];
#pragma unroll
      for (int tb = 0; tb < 4; ++tb) s[tb] = MFMA16(kfr[tb], qfr[qt], zf);

      float sv[4][4];
#pragma unroll
      for (int i = 0; i < 4; ++i) {
        sv[0][i] = s[0][i] + B0[i];
        sv[1][i] = s[1][i] + B1[i];
        sv[2][i] = s[2][i] + B2[i];
        // tb=3: k = 48 + g*4 + i -> only (g==0,i==0) is a real key
        sv[3][i] = (g == 0 && i == 0) ? s[3][0] + B3[0] : -3.0e38f;
      }
      float mx = -3.0e38f;
#pragma unroll
      for (int tb = 0; tb < 4; ++tb)
#pragma unroll
        for (int i = 0; i < 4; ++i) mx = fmaxf(mx, sv[tb][i]);
      mx = fmaxf(mx, __shfl_xor(mx, 16));
      mx = fmaxf(mx, __shfl_xor(mx, 32));
      float sum = 0.f;
#pragma unroll
      for (int tb = 0; tb < 4; ++tb)
#pragma unroll
        for (int i = 0; i < 4; ++i) {
          float e = __expf(sv[tb][i] - mx);
          sv[tb][i] = e;
          sum += e;
        }
      sum += __shfl_xor(sum, 16);
      sum += __shfl_xor(sum, 32);
      float inv = 1.0f / sum;

      bf16x8 pfr[2];
#pragma unroll
      for (int t = 0; t < 2; ++t) {
        f32x4 lo = {sv[2 * t][0] * inv, sv[2 * t][1] * inv, sv[2 * t][2] * inv, sv[2 * t][3] * inv};
        f32x4 hi = {sv[2 * t + 1][0] * inv, sv[2 * t + 1][1] * inv, sv[2 * t + 1][2] * inv, sv[2 * t + 1][3] * inv};
        pfr[t] = pack8(lo, hi);
      }
      f32x4 o0 = zf, o1 = zf;
      o0 = MFMA16(pfr[0], vfr[0][0], o0); o0 = MFMA16(pfr[1], vfr[1][0], o0);
      o1 = MFMA16(pfr[0], vfr[0][1], o1); o1 = MFMA16(pfr[1], vfr[1][1], o1);
#pragma unroll
      for (int i = 0; i < 4; ++i) {
        int r = qt * 16 + g * 4 + i;
        if (r < 49) {
          OALL[r * 392 + h * 32 + m16]      = f2bf(o0[i]);
          OALL[r * 392 + h * 32 + 16 + m16] = f2bf(o1[i]);
        }
      }
    }
  }
  __syncthreads();   // [#3] OALL complete

  // ====== out-projection: wave (qg2 = u>>3, cg = u&7): 2 q-tiles x 3 col-tiles,
  // ping-pong bw prefetch. bw redundancy across waves: 2x (was 4x).
  {
    const int qg2 = u >> 3;        // 0..1 -> q-tiles qg2*2 .. qg2*2+1
    const int cg  = u & 7;         // 0..7 -> col-tiles cg*3 .. cg*3+2
    f32x4 pacc[2][3];
#pragma unroll
    for (int q2 = 0; q2 < 2; ++q2)
#pragma unroll
      for (int c = 0; c < 3; ++c) pacc[q2][c] = zf;

    const short* wp0 = wpT + (size_t)((cg * 3 + 0) * 16 + m16) * 384;
    const short* wp1 = wpT + (size_t)((cg * 3 + 1) * 16 + m16) * 384;
    const short* wp2 = wpT + (size_t)((cg * 3 + 2) * 16 + m16) * 384;
    bf16x8 bA0 = *(const bf16x8*)(wp0 + g * 8);
    bf16x8 bA1 = *(const bf16x8*)(wp1 + g * 8);
    bf16x8 bA2 = *(const bf16x8*)(wp2 + g * 8);
    int r0 = qg2 * 32 + m16;                     // always < 49
    int r1 = qg2 * 32 + 16 + m16; r1 = r1 < 49 ? r1 : 48;
#pragma unroll 1
    for (int kk = 0; kk < 12; kk += 2) {
      const int koB = (kk + 1) * 32 + g * 8;
      bf16x8 bB0 = *(const bf16x8*)(wp0 + koB);
      bf16x8 bB1 = *(const bf16x8*)(wp1 + koB);
      bf16x8 bB2 = *(const bf16x8*)(wp2 + koB);
      {
        const int ko = kk * 32 + g * 8;
        bf16x8 af0 = *(const bf16x8*)(&OALL[r0 * 392 + ko]);
        bf16x8 af1 = *(const bf16x8*)(&OALL[r1 * 392 + ko]);
        pacc[0][0] = MFMA16(af0, bA0, pacc[0][0]);
        pacc[0][1] = MFMA16(af0, bA1, pacc[0][1]);
        pacc[0][2] = MFMA16(af0, bA2, pacc[0][2]);
        pacc[1][0] = MFMA16(af1, bA0, pacc[1][0]);
        pacc[1][1] = MFMA16(af1, bA1, pacc[1][1]);
        pacc[1][2] = MFMA16(af1, bA2, pacc[1][2]);
      }
      const int koA = ((kk + 2) % 12) * 32 + g * 8;
      bA0 = *(const bf16x8*)(wp0 + koA);
      bA1 = *(const bf16x8*)(wp1 + koA);
      bA2 = *(const bf16x8*)(wp2 + koA);
      {
        bf16x8 af0 = *(const bf16x8*)(&OALL[r0 * 392 + koB]);
        bf16x8 af1 = *(const bf16x8*)(&OALL[r1 * 392 + koB]);
        pacc[0][0] = MFMA16(af0, bB0, pacc[0][0]);
        pacc[0][1] = MFMA16(af0, bB1, pacc[0][1]);
        pacc[0][2] = MFMA16(af0, bB2, pacc[0][2]);
        pacc[1][0] = MFMA16(af1, bB0, pacc[1][0]);
        pacc[1][1] = MFMA16(af1, bB1, pacc[1][1]);
        pacc[1][2] = MFMA16(af1, bB2, pacc[1][2]);
      }
    }
    float* outw = out + (size_t)b * (NTOK * DIM);
#pragma unroll
    for (int c = 0; c < 3; ++c) {
      int col = (cg * 3 + c) * 16 + m16;
      float pbv = pb[col];
#pragma unroll
      for (int q2 = 0; q2 < 2; ++q2)
#pragma unroll
        for (int i = 0; i < 4; ++i) {
          int r = qg2 * 32 + q2 * 16 + g * 4 + i;
          if (r < 49) outw[r * DIM + col] = pacc[q2][c][i] + pbv;
        }
    }
  }
}

extern "C" void kernel_launch(void* const* d_in, const int* in_sizes, int n_in,
                              void* d_out, int out_size, void* d_ws, size_t ws_size,
                              hipStream_t stream) {
  const float* xe  = (const float*)d_in[0];
  const float* xb  = (const float*)d_in[1];
  const float* qw  = (const float*)d_in[2];
  const float* qb  = (const float*)d_in[3];
  const float* kvw = (const float*)d_in[4];
  const float* kvb = (const float*)d_in[5];
  const float* pw  = (const float*)d_in[6];
  const float* pb  = (const float*)d_in[7];
  const float* bt  = (const float*)d_in[8];
  float* out = (float*)d_out;
  short* wsS = (short*)d_ws;
  float* biasf = (float*)((char*)d_ws + BIAS_BYTE_OFF);

  const int nwin = in_sizes[0] / (NTOK * DIM);

  const int prep_items = 384 * 384 + 768 * 384 + 384 * 384 + BIAS_ITEMS;
  prep_kernel<<<(prep_items + 255) / 256, 256, 0, stream>>>(qw, kvw, pw, bt, wsS, biasf);

  hipFuncSetAttribute((const void*)fused_kernel,
                      hipFuncAttributeMaxDynamicSharedMemorySize, LDS_BYTES);
  fused_kernel<<<nwin, 1024, LDS_BYTES, stream>>>(
      xe, xb, qb, kvb, pb,
      wsS + WQT_OFF, wsS + WKVT_OFF, wsS + WPT_OFF, biasf, out);
}

// Round 12
// 787.980 us; speedup vs baseline: 1.4669x; 1.2059x over previous
//
#include <hip/hip_runtime.h>
#include <hip/hip_bf16.h>

#define NTOK 49
#define DIM 384
#define HEADS 12
#define SCALE 0.17677669529663687f

typedef __attribute__((ext_vector_type(8))) short bf16x8;
typedef __attribute__((ext_vector_type(4))) float f32x4;

#define MFMA16(a, b, c) __builtin_amdgcn_mfma_f32_16x16x32_bf16((a), (b), (c), 0, 0, 0)

__device__ __forceinline__ short f2bf(float f) {
  __hip_bfloat16 h = __float2bfloat16(f);
  return __builtin_bit_cast(short, h);
}

// Full-K=32 fragment from two K=16 C-tile slices (same relabel on A and B -> exact).
__device__ __forceinline__ bf16x8 pack8(f32x4 a, f32x4 b) {
  bf16x8 r;
#pragma unroll
  for (int i = 0; i < 4; ++i) { r[i] = f2bf(a[i]); r[i + 4] = f2bf(b[i]); }
  return r;
}

// ws layout:
//   wqT  : short [384][384]   elem off 0        (Wq^T row-major [n][k])
//   wkvT : short [768][384]   elem off 147456   (rows 0-383 K, 384-767 V)
//   wpT  : short [384][384]   elem off 442368
//   biasf: float [12][4][4][64][4] byte off 1179648  (fragment-ordered, coalesced)
#define WQT_OFF   0
#define WKVT_OFF  147456
#define WPT_OFF   442368
#define BIAS_BYTE_OFF 1179648
#define BIAS_ITEMS (12 * 4 * 4 * 64 * 4)

__global__ void prep_kernel(const float* __restrict__ qw, const float* __restrict__ kvw,
                            const float* __restrict__ pw, const float* __restrict__ bt,
                            short* __restrict__ wsS, float* __restrict__ biasf) {
  int id = blockIdx.x * 256 + threadIdx.x;
  const int SZ1 = 384 * 384;
  const int SZ2 = 768 * 384;
  const int SZ3 = 384 * 384;
  if (id < SZ1) {
    int n = id / 384, k = id % 384;
    wsS[WQT_OFF + id] = f2bf(qw[k * 384 + n]);
  } else if (id < SZ1 + SZ2) {
    int t = id - SZ1; int n = t / 384, k = t % 384;
    wsS[WKVT_OFF + t] = f2bf(kvw[k * 768 + n]);
  } else if (id < SZ1 + SZ2 + SZ3) {
    int t = id - (SZ1 + SZ2); int n = t / 384, k = t % 384;
    wsS[WPT_OFF + t] = f2bf(pw[k * 384 + n]);
  } else if (id < SZ1 + SZ2 + SZ3 + BIAS_ITEMS) {
    int t = id - (SZ1 + SZ2 + SZ3);
    // [h][qt][tb][l][i]: lane l of fragment (qt,tb) element i
    int i  = t & 3;
    int lm = (t >> 2) & 63;
    int tb = (t >> 8) & 3;
    int qt = (t >> 10) & 3;
    int h  = t >> 12;
    int q = qt * 16 + (lm & 15);
    int k = tb * 16 + (lm >> 4) * 4 + i;
    float v = 0.0f;
    if (q < NTOK && k < NTOK) {
      int idx = ((q / 7 - k / 7) + 6) * 13 + ((q % 7 - k % 7) + 6);
      v = bt[idx * HEADS + h];
    }
    biasf[t] = v;
  }
}

// LDS (shorts). Row stride 392 shorts = 196 dw == 4 mod 32: 16-row b128 frag
// reads land 2 lanes/bank (free).
#define LDS_ELEMS 38416
#define LDS_BYTES (LDS_ELEMS * 2)   // 76832 B -> 2 blocks/CU (153664 <= 160K)

// cap model (fits R2/R6/R7/R10/R11): cap = 512/(ceil(wpb/4)*arg).
// (256,2): ceil(4/4)*2 = 2 -> 256 VGPRs, 2 blocks/CU guaranteed.
__global__ __launch_bounds__(256, 2)
void fused_kernel(const float* __restrict__ xe, const float* __restrict__ xb,
                  const float* __restrict__ qb, const float* __restrict__ kvb,
                  const float* __restrict__ pb,
                  const short* __restrict__ wqT, const short* __restrict__ wkvT,
                  const short* __restrict__ wpT, const float* __restrict__ biasf,
                  float* __restrict__ out) {
  extern __shared__ short lds[];
  short* X    = lds;             // x_body
  short* XE   = lds + 19208;     // x_edge; becomes OALL after barrier #2
  short* OALL = XE;

  const int b   = blockIdx.x;
  const int tid = threadIdx.x;
  const int u   = tid >> 6;      // wave 0..3, owns heads 3u..3u+2
  const int l   = tid & 63;
  const int m16 = l & 15;
  const int g   = l >> 4;

  const f32x4 zf = {0.f, 0.f, 0.f, 0.f};

  // ---- stage x_edge -> XE and x_body -> X ----
  const float* xew = xe + (size_t)b * (NTOK * DIM);
  const float* xbw = xb + (size_t)b * (NTOK * DIM);
  for (int i4 = tid; i4 < 2 * 4704; i4 += 256) {
    int eb = i4 < 4704;
    int e = (eb ? i4 : i4 - 4704) * 4;
    const float* src = eb ? xew : xbw;
    short* dst = eb ? XE : X;
    int r = e / DIM, c = e % DIM;
    float4 v = *(const float4*)(src + e);
    ushort4 s;
    s.x = (unsigned short)f2bf(v.x); s.y = (unsigned short)f2bf(v.y);
    s.z = (unsigned short)f2bf(v.z); s.w = (unsigned short)f2bf(v.w);
    *(ushort4*)&dst[r * 392 + c] = s;
  }
  __syncthreads();   // [#1]

  bf16x8 ofr[3][4];  // deferred O frags: [head][qt], elems 0-3 = o0, 4-7 = o1

#pragma unroll
  for (int hh = 0; hh < 3; ++hh) {
    const int h = u * 3 + hh;

    // ============ merged Q+K+V GEMM (ping-pong weight prefetch) ============
    f32x4 qc0[4], qc1[4], kc0[4], kc1[4], vc0[4], vc1[4];
#pragma unroll
    for (int tb = 0; tb < 4; ++tb) {
      qc0[tb] = zf; qc1[tb] = zf; kc0[tb] = zf;
      kc1[tb] = zf; vc0[tb] = zf; vc1[tb] = zf;
    }
    const short* wq0 = wqT  + (size_t)(h * 32 + m16) * 384;
    const short* wq1 = wqT  + (size_t)(h * 32 + 16 + m16) * 384;
    const short* wk0 = wkvT + (size_t)(h * 32 + m16) * 384;
    const short* wk1 = wkvT + (size_t)(h * 32 + 16 + m16) * 384;
    const short* wv0 = wkvT + (size_t)(384 + h * 32 + m16) * 384;
    const short* wv1 = wkvT + (size_t)(384 + h * 32 + 16 + m16) * 384;
    bf16x8 qA0 = *(const bf16x8*)(wq0 + g * 8), qA1 = *(const bf16x8*)(wq1 + g * 8);
    bf16x8 kA0 = *(const bf16x8*)(wk0 + g * 8), kA1 = *(const bf16x8*)(wk1 + g * 8);
    bf16x8 vA0 = *(const bf16x8*)(wv0 + g * 8), vA1 = *(const bf16x8*)(wv1 + g * 8);
#pragma unroll 1
    for (int kk = 0; kk < 12; kk += 2) {
      const int koB = (kk + 1) * 32 + g * 8;
      bf16x8 qB0 = *(const bf16x8*)(wq0 + koB), qB1 = *(const bf16x8*)(wq1 + koB);
      bf16x8 kB0 = *(const bf16x8*)(wk0 + koB), kB1 = *(const bf16x8*)(wk1 + koB);
      bf16x8 vB0 = *(const bf16x8*)(wv0 + koB), vB1 = *(const bf16x8*)(wv1 + koB);
      {
        const int ko = kk * 32 + g * 8;
#pragma unroll
        for (int tb = 0; tb < 4; ++tb) {
          int tr = tb * 16 + m16; tr = tr < 49 ? tr : 48;
          bf16x8 xev = *(const bf16x8*)(&XE[tr * 392 + ko]);
          bf16x8 xbv = *(const bf16x8*)(&X[tr * 392 + ko]);
          qc0[tb] = MFMA16(qA0, xev, qc0[tb]);
          qc1[tb] = MFMA16(qA1, xev, qc1[tb]);
          kc0[tb] = MFMA16(kA0, xbv, kc0[tb]);
          kc1[tb] = MFMA16(kA1, xbv, kc1[tb]);
          vc0[tb] = MFMA16(xbv, vA0, vc0[tb]);
          vc1[tb] = MFMA16(xbv, vA1, vc1[tb]);
        }
      }
      const int koA = ((kk + 2) % 12) * 32 + g * 8;   // wrap: harmless dead load
      qA0 = *(const bf16x8*)(wq0 + koA); qA1 = *(const bf16x8*)(wq1 + koA);
      kA0 = *(const bf16x8*)(wk0 + koA); kA1 = *(const bf16x8*)(wk1 + koA);
      vA0 = *(const bf16x8*)(wv0 + koA); vA1 = *(const bf16x8*)(wv1 + koA);
      {
#pragma unroll
        for (int tb = 0; tb < 4; ++tb) {
          int tr = tb * 16 + m16; tr = tr < 49 ? tr : 48;
          bf16x8 xev = *(const bf16x8*)(&XE[tr * 392 + koB]);
          bf16x8 xbv = *(const bf16x8*)(&X[tr * 392 + koB]);
          qc0[tb] = MFMA16(qB0, xev, qc0[tb]);
          qc1[tb] = MFMA16(qB1, xev, qc1[tb]);
          kc0[tb] = MFMA16(kB0, xbv, kc0[tb]);
          kc1[tb] = MFMA16(kB1, xbv, kc1[tb]);
          vc0[tb] = MFMA16(xbv, vB0, vc0[tb]);
          vc1[tb] = MFMA16(xbv, vB1, vc1[tb]);
        }
      }
    }
    // ---- fold biases, pack fragments ----
    bf16x8 qfr[4], kfr[4], vfr[2][2];
    {
      float4 t0 = *(const float4*)(qb + h * 32 + g * 4);
      float4 t1 = *(const float4*)(qb + h * 32 + 16 + g * 4);
      f32x4 b0 = {t0.x, t0.y, t0.z, t0.w};
      f32x4 b1 = {t1.x, t1.y, t1.z, t1.w};
#pragma unroll
      for (int qt = 0; qt < 4; ++qt)
        qfr[qt] = pack8((qc0[qt] + b0) * SCALE, (qc1[qt] + b1) * SCALE);
    }
    {
      float4 t0 = *(const float4*)(kvb + h * 32 + g * 4);
      float4 t1 = *(const float4*)(kvb + h * 32 + 16 + g * 4);
      f32x4 b0 = {t0.x, t0.y, t0.z, t0.w};
      f32x4 b1 = {t1.x, t1.y, t1.z, t1.w};
#pragma unroll
      for (int tb = 0; tb < 4; ++tb) kfr[tb] = pack8(kc0[tb] + b0, kc1[tb] + b1);
    }
    {
      float vb0 = kvb[384 + h * 32 + m16];
      float vb1 = kvb[384 + h * 32 + 16 + m16];
      f32x4 bv0 = {vb0, vb0, vb0, vb0};
      f32x4 bv1 = {vb1, vb1, vb1, vb1};
#pragma unroll
      for (int t = 0; t < 2; ++t) {
        vfr[t][0] = pack8(vc0[2 * t] + bv0, vc0[2 * t + 1] + bv0);
        vfr[t][1] = pack8(vc1[2 * t] + bv1, vc1[2 * t + 1] + bv1);
      }
    }

    // ============ attention per q-tile ============
    const float4* bfh = (const float4*)biasf + (size_t)h * 4 * 4 * 64;
#pragma unroll
    for (int qt = 0; qt < 4; ++qt) {
      const float4* bq = bfh + qt * 4 * 64;
      float4 c0 = bq[l], c1 = bq[64 + l], c2 = bq[128 + l], c3 = bq[192 + l];
      f32x4 B0 = {c0.x, c0.y, c0.z, c0.w};
      f32x4 B1 = {c1.x, c1.y, c1.z, c1.w};
      f32x4 B2 = {c2.x, c2.y, c2.z, c2.w};
      f32x4 B3 = {c3.x, c3.y, c3.z, c3.w};
      f32x4 s[4];
#pragma unroll
      for (int tb = 0; tb < 4; ++tb) s[tb] = MFMA16(kfr[tb], qfr[qt], zf);

      float sv[4][4];
#pragma unroll
      for (int i = 0; i < 4; ++i) {
        sv[0][i] = s[0][i] + B0[i];
        sv[1][i] = s[1][i] + B1[i];
        sv[2][i] = s[2][i] + B2[i];
        // tb=3: k = 48 + g*4 + i -> only (g==0,i==0) is a real key
        sv[3][i] = (g == 0 && i == 0) ? s[3][0] + B3[0] : -3.0e38f;
      }
      float mx = -3.0e38f;
#pragma unroll
      for (int tb = 0; tb < 4; ++tb)
#pragma unroll
        for (int i = 0; i < 4; ++i) mx = fmaxf(mx, sv[tb][i]);
      mx = fmaxf(mx, __shfl_xor(mx, 16));
      mx = fmaxf(mx, __shfl_xor(mx, 32));
      float sum = 0.f;
#pragma unroll
      for (int tb = 0; tb < 4; ++tb)
#pragma unroll
        for (int i = 0; i < 4; ++i) {
          float e = __expf(sv[tb][i] - mx);
          sv[tb][i] = e;
          sum += e;
        }
      sum += __shfl_xor(sum, 16);
      sum += __shfl_xor(sum, 32);
      float inv = 1.0f / sum;

      bf16x8 pfr[2];
#pragma unroll
      for (int t = 0; t < 2; ++t) {
        f32x4 lo = {sv[2 * t][0] * inv, sv[2 * t][1] * inv, sv[2 * t][2] * inv, sv[2 * t][3] * inv};
        f32x4 hi = {sv[2 * t + 1][0] * inv, sv[2 * t + 1][1] * inv, sv[2 * t + 1][2] * inv, sv[2 * t + 1][3] * inv};
        pfr[t] = pack8(lo, hi);
      }
      f32x4 o0 = zf, o1 = zf;
      o0 = MFMA16(pfr[0], vfr[0][0], o0); o0 = MFMA16(pfr[1], vfr[1][0], o0);
      o1 = MFMA16(pfr[0], vfr[0][1], o1); o1 = MFMA16(pfr[1], vfr[1][1], o1);
      ofr[hh][qt] = pack8(o0, o1);   // defer LDS write until XE is dead
    }
  }
  __syncthreads();   // [#2] all XE reads done -> XE becomes OALL

  // ---- flush deferred O tiles ----
#pragma unroll
  for (int hh = 0; hh < 3; ++hh) {
    const int h = u * 3 + hh;
#pragma unroll
    for (int qt = 0; qt < 4; ++qt)
#pragma unroll
      for (int i = 0; i < 4; ++i) {
        int r = qt * 16 + g * 4 + i;
        if (r < 49) {
          OALL[r * 392 + h * 32 + m16]      = ofr[hh][qt][i];
          OALL[r * 392 + h * 32 + 16 + m16] = ofr[hh][qt][4 + i];
        }
      }
  }
  __syncthreads();   // [#3] OALL complete

  // ====== out-projection: wave u owns col-tiles u*6 .. u*6+5, all 4 q-tiles ==
  {
    f32x4 pacc[4][6];
#pragma unroll
    for (int qt = 0; qt < 4; ++qt)
#pragma unroll
      for (int c = 0; c < 6; ++c) pacc[qt][c] = zf;

    const short* wp[6];
    bf16x8 bA[6];
#pragma unroll
    for (int c = 0; c < 6; ++c) {
      wp[c] = wpT + (size_t)((u * 6 + c) * 16 + m16) * 384;
      bA[c] = *(const bf16x8*)(wp[c] + g * 8);
    }
#pragma unroll 1
    for (int kk = 0; kk < 12; kk += 2) {
      const int koB = (kk + 1) * 32 + g * 8;
      bf16x8 bB[6];
#pragma unroll
      for (int c = 0; c < 6; ++c) bB[c] = *(const bf16x8*)(wp[c] + koB);
      {
        const int ko = kk * 32 + g * 8;
        bf16x8 af[4];
#pragma unroll
        for (int qt = 0; qt < 4; ++qt) {
          int r = qt * 16 + m16; r = r < 49 ? r : 48;
          af[qt] = *(const bf16x8*)(&OALL[r * 392 + ko]);
        }
#pragma unroll
        for (int c = 0; c < 6; ++c)
#pragma unroll
          for (int qt = 0; qt < 4; ++qt) pacc[qt][c] = MFMA16(af[qt], bA[c], pacc[qt][c]);
      }
      const int koA = ((kk + 2) % 12) * 32 + g * 8;
#pragma unroll
      for (int c = 0; c < 6; ++c) bA[c] = *(const bf16x8*)(wp[c] + koA);
      {
        bf16x8 af[4];
#pragma unroll
        for (int qt = 0; qt < 4; ++qt) {
          int r = qt * 16 + m16; r = r < 49 ? r : 48;
          af[qt] = *(const bf16x8*)(&OALL[r * 392 + koB]);
        }
#pragma unroll
        for (int c = 0; c < 6; ++c)
#pragma unroll
          for (int qt = 0; qt < 4; ++qt) pacc[qt][c] = MFMA16(af[qt], bB[c], pacc[qt][c]);
      }
    }
    float* outw = out + (size_t)b * (NTOK * DIM);
#pragma unroll
    for (int c = 0; c < 6; ++c) {
      int col = (u * 6 + c) * 16 + m16;
      float pbv = pb[col];
#pragma unroll
      for (int qt = 0; qt < 4; ++qt)
#pragma unroll
        for (int i = 0; i < 4; ++i) {
          int r = qt * 16 + g * 4 + i;
          if (r < 49) outw[r * DIM + col] = pacc[qt][c][i] + pbv;
        }
    }
  }
}

extern "C" void kernel_launch(void* const* d_in, const int* in_sizes, int n_in,
                              void* d_out, int out_size, void* d_ws, size_t ws_size,
                              hipStream_t stream) {
  const float* xe  = (const float*)d_in[0];
  const float* xb  = (const float*)d_in[1];
  const float* qw  = (const float*)d_in[2];
  const float* qb  = (const float*)d_in[3];
  const float* kvw = (const float*)d_in[4];
  const float* kvb = (const float*)d_in[5];
  const float* pw  = (const float*)d_in[6];
  const float* pb  = (const float*)d_in[7];
  const float* bt  = (const float*)d_in[8];
  float* out = (float*)d_out;
  short* wsS = (short*)d_ws;
  float* biasf = (float*)((char*)d_ws + BIAS_BYTE_OFF);

  const int nwin = in_sizes[0] / (NTOK * DIM);

  const int prep_items = 384 * 384 + 768 * 384 + 384 * 384 + BIAS_ITEMS;
  prep_kernel<<<(prep_items + 255) / 256, 256, 0, stream>>>(qw, kvw, pw, bt, wsS, biasf);

  hipFuncSetAttribute((const void*)fused_kernel,
                      hipFuncAttributeMaxDynamicSharedMemorySize, LDS_BYTES);
  fused_kernel<<<nwin, 256, LDS_BYTES, stream>>>(
      xe, xb, qb, kvb, pb,
      wsS + WQT_OFF, wsS + WKVT_OFF, wsS + WPT_OFF, biasf, out);
}

// Round 13
// 699.508 us; speedup vs baseline: 1.6525x; 1.1265x over previous
//
#include <hip/hip_runtime.h>
#include <hip/hip_bf16.h>

#define NTOK 49
#define DIM 384
#define HEADS 12
#define SCALE 0.17677669529663687f

typedef __attribute__((ext_vector_type(8))) short bf16x8;
typedef __attribute__((ext_vector_type(4))) float f32x4;

#define MFMA16(a, b, c) __builtin_amdgcn_mfma_f32_16x16x32_bf16((a), (b), (c), 0, 0, 0)

__device__ __forceinline__ short f2bf(float f) {
  __hip_bfloat16 h = __float2bfloat16(f);
  return __builtin_bit_cast(short, h);
}

// Full-K=32 fragment from two K=16 C-tile slices (same relabel on A and B -> exact).
__device__ __forceinline__ bf16x8 pack8(f32x4 a, f32x4 b) {
  bf16x8 r;
#pragma unroll
  for (int i = 0; i < 4; ++i) { r[i] = f2bf(a[i]); r[i + 4] = f2bf(b[i]); }
  return r;
}

// ws layout:
//   wqT  : short [384][384]   elem off 0        (Wq^T row-major [n][k])
//   wkvT : short [768][384]   elem off 147456   (rows 0-383 K, 384-767 V)
//   wpT  : short [384][384]   elem off 442368
//   biasf: float [12][4][4][64][4] byte off 1179648  (fragment-ordered, coalesced)
#define WQT_OFF   0
#define WKVT_OFF  147456
#define WPT_OFF   442368
#define BIAS_BYTE_OFF 1179648
#define BIAS_ITEMS (12 * 4 * 4 * 64 * 4)

__global__ void prep_kernel(const float* __restrict__ qw, const float* __restrict__ kvw,
                            const float* __restrict__ pw, const float* __restrict__ bt,
                            short* __restrict__ wsS, float* __restrict__ biasf) {
  int id = blockIdx.x * 256 + threadIdx.x;
  const int SZ1 = 384 * 384;
  const int SZ2 = 768 * 384;
  const int SZ3 = 384 * 384;
  if (id < SZ1) {
    int n = id / 384, k = id % 384;
    wsS[WQT_OFF + id] = f2bf(qw[k * 384 + n]);
  } else if (id < SZ1 + SZ2) {
    int t = id - SZ1; int n = t / 384, k = t % 384;
    wsS[WKVT_OFF + t] = f2bf(kvw[k * 768 + n]);
  } else if (id < SZ1 + SZ2 + SZ3) {
    int t = id - (SZ1 + SZ2); int n = t / 384, k = t % 384;
    wsS[WPT_OFF + t] = f2bf(pw[k * 384 + n]);
  } else if (id < SZ1 + SZ2 + SZ3 + BIAS_ITEMS) {
    int t = id - (SZ1 + SZ2 + SZ3);
    // [h][qt][tb][l][i]: lane l of fragment (qt,tb) element i
    int i  = t & 3;
    int lm = (t >> 2) & 63;
    int tb = (t >> 8) & 3;
    int qt = (t >> 10) & 3;
    int h  = t >> 12;
    int q = qt * 16 + (lm & 15);
    int k = tb * 16 + (lm >> 4) * 4 + i;
    float v = 0.0f;
    if (q < NTOK && k < NTOK) {
      int idx = ((q / 7 - k / 7) + 6) * 13 + ((q % 7 - k % 7) + 6);
      v = bt[idx * HEADS + h];
    }
    biasf[t] = v;
  }
}

// LDS (shorts). Row stride 392 shorts = 196 dw == 4 mod 32: 16-row b128 frag
// reads land 2 lanes/bank (free).
#define LDS_ELEMS 38416
#define LDS_BYTES (LDS_ELEMS * 2)   // 76832 B -> 2 blocks/CU (153664 <= 160K)

// (256,2): 2 blocks/CU, 2 waves/SIMD, 256 regs/wave (VGPR+AGPR unified).
__global__ __launch_bounds__(256, 2)
void fused_kernel(const float* __restrict__ xe, const float* __restrict__ xb,
                  const float* __restrict__ qb, const float* __restrict__ kvb,
                  const float* __restrict__ pb,
                  const short* __restrict__ wqT, const short* __restrict__ wkvT,
                  const short* __restrict__ wpT, const float* __restrict__ biasf,
                  float* __restrict__ out) {
  extern __shared__ short lds[];
  short* X    = lds;             // x_body
  short* XE   = lds + 19208;     // x_edge; becomes OALL after barrier #2
  short* OALL = XE;

  const int b   = blockIdx.x;
  const int tid = threadIdx.x;
  const int u   = tid >> 6;      // wave 0..3, owns heads 3u..3u+2
  const int l   = tid & 63;
  const int m16 = l & 15;
  const int g   = l >> 4;
  const int h0  = u * 3;

  const f32x4 zf = {0.f, 0.f, 0.f, 0.f};

  // ---- stage x_edge -> XE and x_body -> X ----
  const float* xew = xe + (size_t)b * (NTOK * DIM);
  const float* xbw = xb + (size_t)b * (NTOK * DIM);
#pragma unroll 4
  for (int i4 = tid; i4 < 2 * 4704; i4 += 256) {
    int eb = i4 < 4704;
    int e = (eb ? i4 : i4 - 4704) * 4;
    const float* src = eb ? xew : xbw;
    short* dst = eb ? XE : X;
    int r = e / DIM, c = e % DIM;
    float4 v = *(const float4*)(src + e);
    ushort4 s;
    s.x = (unsigned short)f2bf(v.x); s.y = (unsigned short)f2bf(v.y);
    s.z = (unsigned short)f2bf(v.z); s.w = (unsigned short)f2bf(v.w);
    *(ushort4*)&dst[r * 392 + c] = s;
  }
  __syncthreads();   // [#1]

  // ============ Q pass: merged 3 heads (6 weight streams, ping-pong) =========
  bf16x8 qfr[3][4];
  {
    f32x4 qc[6][4];   // t = hh*2 + dt
#pragma unroll
    for (int t = 0; t < 6; ++t)
#pragma unroll
      for (int tb = 0; tb < 4; ++tb) qc[t][tb] = zf;

    const short* wq[6];
    bf16x8 wA[6];
#pragma unroll
    for (int t = 0; t < 6; ++t) {
      wq[t] = wqT + (size_t)((h0 + (t >> 1)) * 32 + (t & 1) * 16 + m16) * 384;
      wA[t] = *(const bf16x8*)(wq[t] + g * 8);
    }
#pragma unroll 1
    for (int kk = 0; kk < 12; kk += 2) {
      const int koB = (kk + 1) * 32 + g * 8;
      bf16x8 wB[6];
#pragma unroll
      for (int t = 0; t < 6; ++t) wB[t] = *(const bf16x8*)(wq[t] + koB);
      {
        const int ko = kk * 32 + g * 8;
#pragma unroll
        for (int tb = 0; tb < 4; ++tb) {
          int tr = tb * 16 + m16; tr = tr < 49 ? tr : 48;
          bf16x8 xv = *(const bf16x8*)(&XE[tr * 392 + ko]);
#pragma unroll
          for (int t = 0; t < 6; ++t) qc[t][tb] = MFMA16(wA[t], xv, qc[t][tb]);
        }
      }
      const int koA = ((kk + 2) % 12) * 32 + g * 8;   // wrap: harmless dead load
#pragma unroll
      for (int t = 0; t < 6; ++t) wA[t] = *(const bf16x8*)(wq[t] + koA);
      {
#pragma unroll
        for (int tb = 0; tb < 4; ++tb) {
          int tr = tb * 16 + m16; tr = tr < 49 ? tr : 48;
          bf16x8 xv = *(const bf16x8*)(&XE[tr * 392 + koB]);
#pragma unroll
          for (int t = 0; t < 6; ++t) qc[t][tb] = MFMA16(wB[t], xv, qc[t][tb]);
        }
      }
    }
#pragma unroll
    for (int hh = 0; hh < 3; ++hh) {
      const int h = h0 + hh;
      float4 t0 = *(const float4*)(qb + h * 32 + g * 4);
      float4 t1 = *(const float4*)(qb + h * 32 + 16 + g * 4);
      f32x4 b0 = {t0.x, t0.y, t0.z, t0.w};
      f32x4 b1 = {t1.x, t1.y, t1.z, t1.w};
#pragma unroll
      for (int qt = 0; qt < 4; ++qt)
        qfr[hh][qt] = pack8((qc[hh * 2][qt] + b0) * SCALE, (qc[hh * 2 + 1][qt] + b1) * SCALE);
    }
  }
  __syncthreads();   // [#2] all XE reads done -> XE becomes OALL

  // ======== per head: merged K+V GEMM (weight + xv ping-pong) + attention ====
#pragma unroll
  for (int hh = 0; hh < 3; ++hh) {
    const int h = h0 + hh;

    f32x4 kc0[4], kc1[4], vc0[4], vc1[4];
#pragma unroll
    for (int tb = 0; tb < 4; ++tb) { kc0[tb] = zf; kc1[tb] = zf; vc0[tb] = zf; vc1[tb] = zf; }
    const short* wk0 = wkvT + (size_t)(h * 32 + m16) * 384;
    const short* wk1 = wkvT + (size_t)(h * 32 + 16 + m16) * 384;
    const short* wv0 = wkvT + (size_t)(384 + h * 32 + m16) * 384;
    const short* wv1 = wkvT + (size_t)(384 + h * 32 + 16 + m16) * 384;
    bf16x8 kA0 = *(const bf16x8*)(wk0 + g * 8), kA1 = *(const bf16x8*)(wk1 + g * 8);
    bf16x8 vA0 = *(const bf16x8*)(wv0 + g * 8), vA1 = *(const bf16x8*)(wv1 + g * 8);
    bf16x8 xbA[4];
#pragma unroll
    for (int tb = 0; tb < 4; ++tb) {
      int tr = tb * 16 + m16; tr = tr < 49 ? tr : 48;
      xbA[tb] = *(const bf16x8*)(&X[tr * 392 + g * 8]);
    }
#pragma unroll 1
    for (int kk = 0; kk < 12; kk += 2) {
      const int koB = (kk + 1) * 32 + g * 8;
      bf16x8 kB0 = *(const bf16x8*)(wk0 + koB), kB1 = *(const bf16x8*)(wk1 + koB);
      bf16x8 vB0 = *(const bf16x8*)(wv0 + koB), vB1 = *(const bf16x8*)(wv1 + koB);
      bf16x8 xbB[4];
#pragma unroll
      for (int tb = 0; tb < 4; ++tb) {
        int tr = tb * 16 + m16; tr = tr < 49 ? tr : 48;
        xbB[tb] = *(const bf16x8*)(&X[tr * 392 + koB]);
      }
      // compute half A
#pragma unroll
      for (int tb = 0; tb < 4; ++tb) {
        kc0[tb] = MFMA16(kA0, xbA[tb], kc0[tb]);
        kc1[tb] = MFMA16(kA1, xbA[tb], kc1[tb]);
        vc0[tb] = MFMA16(xbA[tb], vA0, vc0[tb]);
        vc1[tb] = MFMA16(xbA[tb], vA1, vc1[tb]);
      }
      const int koA = ((kk + 2) % 12) * 32 + g * 8;   // wrap: harmless dead load
      kA0 = *(const bf16x8*)(wk0 + koA); kA1 = *(const bf16x8*)(wk1 + koA);
      vA0 = *(const bf16x8*)(wv0 + koA); vA1 = *(const bf16x8*)(wv1 + koA);
#pragma unroll
      for (int tb = 0; tb < 4; ++tb) {
        int tr = tb * 16 + m16; tr = tr < 49 ? tr : 48;
        xbA[tb] = *(const bf16x8*)(&X[tr * 392 + koA]);
      }
      // compute half B
#pragma unroll
      for (int tb = 0; tb < 4; ++tb) {
        kc0[tb] = MFMA16(kB0, xbB[tb], kc0[tb]);
        kc1[tb] = MFMA16(kB1, xbB[tb], kc1[tb]);
        vc0[tb] = MFMA16(xbB[tb], vB0, vc0[tb]);
        vc1[tb] = MFMA16(xbB[tb], vB1, vc1[tb]);
      }
    }
    // ---- fold biases, pack fragments ----
    bf16x8 kfr[4], vfr[2][2];
    {
      float4 t0 = *(const float4*)(kvb + h * 32 + g * 4);
      float4 t1 = *(const float4*)(kvb + h * 32 + 16 + g * 4);
      f32x4 b0 = {t0.x, t0.y, t0.z, t0.w};
      f32x4 b1 = {t1.x, t1.y, t1.z, t1.w};
#pragma unroll
      for (int tb = 0; tb < 4; ++tb) kfr[tb] = pack8(kc0[tb] + b0, kc1[tb] + b1);
    }
    {
      float vb0 = kvb[384 + h * 32 + m16];
      float vb1 = kvb[384 + h * 32 + 16 + m16];
      f32x4 bv0 = {vb0, vb0, vb0, vb0};
      f32x4 bv1 = {vb1, vb1, vb1, vb1};
#pragma unroll
      for (int t = 0; t < 2; ++t) {
        vfr[t][0] = pack8(vc0[2 * t] + bv0, vc0[2 * t + 1] + bv0);
        vfr[t][1] = pack8(vc1[2 * t] + bv1, vc1[2 * t + 1] + bv1);
      }
    }

    // ============ attention per q-tile; O flushed immediately ============
    const float4* bfh = (const float4*)biasf + (size_t)h * 4 * 4 * 64;
#pragma unroll
    for (int qt = 0; qt < 4; ++qt) {
      const float4* bq = bfh + qt * 4 * 64;
      float4 c0 = bq[l], c1 = bq[64 + l], c2 = bq[128 + l], c3 = bq[192 + l];
      f32x4 B0 = {c0.x, c0.y, c0.z, c0.w};
      f32x4 B1 = {c1.x, c1.y, c1.z, c1.w};
      f32x4 B2 = {c2.x, c2.y, c2.z, c2.w};
      f32x4 B3 = {c3.x, c3.y, c3.z, c3.w};
      f32x4 s[4];
#pragma unroll
      for (int tb = 0; tb < 4; ++tb) s[tb] = MFMA16(kfr[tb], qfr[hh][qt], zf);

      float sv[4][4];
#pragma unroll
      for (int i = 0; i < 4; ++i) {
        sv[0][i] = s[0][i] + B0[i];
        sv[1][i] = s[1][i] + B1[i];
        sv[2][i] = s[2][i] + B2[i];
        // tb=3: k = 48 + g*4 + i -> only (g==0,i==0) is a real key
        sv[3][i] = (g == 0 && i == 0) ? s[3][0] + B3[0] : -3.0e38f;
      }
      float mx = -3.0e38f;
#pragma unroll
      for (int tb = 0; tb < 4; ++tb)
#pragma unroll
        for (int i = 0; i < 4; ++i) mx = fmaxf(mx, sv[tb][i]);
      mx = fmaxf(mx, __shfl_xor(mx, 16));
      mx = fmaxf(mx, __shfl_xor(mx, 32));
      float sum = 0.f;
#pragma unroll
      for (int tb = 0; tb < 4; ++tb)
#pragma unroll
        for (int i = 0; i < 4; ++i) {
          float e = __expf(sv[tb][i] - mx);
          sv[tb][i] = e;
          sum += e;
        }
      sum += __shfl_xor(sum, 16);
      sum += __shfl_xor(sum, 32);
      float inv = 1.0f / sum;

      bf16x8 pfr[2];
#pragma unroll
      for (int t = 0; t < 2; ++t) {
        f32x4 lo = {sv[2 * t][0] * inv, sv[2 * t][1] * inv, sv[2 * t][2] * inv, sv[2 * t][3] * inv};
        f32x4 hi = {sv[2 * t + 1][0] * inv, sv[2 * t + 1][1] * inv, sv[2 * t + 1][2] * inv, sv[2 * t + 1][3] * inv};
        pfr[t] = pack8(lo, hi);
      }
      f32x4 o0 = zf, o1 = zf;
      o0 = MFMA16(pfr[0], vfr[0][0], o0); o0 = MFMA16(pfr[1], vfr[1][0], o0);
      o1 = MFMA16(pfr[0], vfr[0][1], o1); o1 = MFMA16(pfr[1], vfr[1][1], o1);
#pragma unroll
      for (int i = 0; i < 4; ++i) {
        int r = qt * 16 + g * 4 + i;
        if (r < 49) {
          OALL[r * 392 + h * 32 + m16]      = f2bf(o0[i]);
          OALL[r * 392 + h * 32 + 16 + m16] = f2bf(o1[i]);
        }
      }
    }
  }
  __syncthreads();   // [#3] OALL complete

  // ====== out-projection: wave u owns col-tiles u*6..u*6+5 (af + bw ping-pong)
  {
    f32x4 pacc[4][6];
#pragma unroll
    for (int qt = 0; qt < 4; ++qt)
#pragma unroll
      for (int c = 0; c < 6; ++c) pacc[qt][c] = zf;

    int rq[4];
#pragma unroll
    for (int qt = 0; qt < 4; ++qt) {
      int r = qt * 16 + m16; rq[qt] = r < 49 ? r : 48;
    }
    const short* wp[6];
    bf16x8 bA[6];
#pragma unroll
    for (int c = 0; c < 6; ++c) {
      wp[c] = wpT + (size_t)((u * 6 + c) * 16 + m16) * 384;
      bA[c] = *(const bf16x8*)(wp[c] + g * 8);
    }
    bf16x8 afA[4];
#pragma unroll
    for (int qt = 0; qt < 4; ++qt) afA[qt] = *(const bf16x8*)(&OALL[rq[qt] * 392 + g * 8]);
#pragma unroll 1
    for (int kk = 0; kk < 12; kk += 2) {
      const int koB = (kk + 1) * 32 + g * 8;
      bf16x8 bB[6];
#pragma unroll
      for (int c = 0; c < 6; ++c) bB[c] = *(const bf16x8*)(wp[c] + koB);
      bf16x8 afB[4];
#pragma unroll
      for (int qt = 0; qt < 4; ++qt) afB[qt] = *(const bf16x8*)(&OALL[rq[qt] * 392 + koB]);
      // half A
#pragma unroll
      for (int c = 0; c < 6; ++c)
#pragma unroll
        for (int qt = 0; qt < 4; ++qt) pacc[qt][c] = MFMA16(afA[qt], bA[c], pacc[qt][c]);
      const int koA = ((kk + 2) % 12) * 32 + g * 8;
#pragma unroll
      for (int c = 0; c < 6; ++c) bA[c] = *(const bf16x8*)(wp[c] + koA);
#pragma unroll
      for (int qt = 0; qt < 4; ++qt) afA[qt] = *(const bf16x8*)(&OALL[rq[qt] * 392 + koA]);
      // half B
#pragma unroll
      for (int c = 0; c < 6; ++c)
#pragma unroll
        for (int qt = 0; qt < 4; ++qt) pacc[qt][c] = MFMA16(afB[qt], bB[c], pacc[qt][c]);
    }
    float* outw = out + (size_t)b * (NTOK * DIM);
#pragma unroll
    for (int c = 0; c < 6; ++c) {
      int col = (u * 6 + c) * 16 + m16;
      float pbv = pb[col];
#pragma unroll
      for (int qt = 0; qt < 4; ++qt)
#pragma unroll
        for (int i = 0; i < 4; ++i) {
          int r = qt * 16 + g * 4 + i;
          if (r < 49) outw[r * DIM + col] = pacc[qt][c][i] + pbv;
        }
    }
  }
}

extern "C" void kernel_launch(void* const* d_in, const int* in_sizes, int n_in,
                              void* d_out, int out_size, void* d_ws, size_t ws_size,
                              hipStream_t stream) {
  const float* xe  = (const float*)d_in[0];
  const float* xb  = (const float*)d_in[1];
  const float* qw  = (const float*)d_in[2];
  const float* qb  = (const float*)d_in[3];
  const float* kvw = (const float*)d_in[4];
  const float* kvb = (const float*)d_in[5];
  const float* pw  = (const float*)d_in[6];
  const float* pb  = (const float*)d_in[7];
  const float* bt  = (const float*)d_in[8];
  float* out = (float*)d_out;
  short* wsS = (short*)d_ws;
  float* biasf = (float*)((char*)d_ws + BIAS_BYTE_OFF);

  const int nwin = in_sizes[0] / (NTOK * DIM);

  const int prep_items = 384 * 384 + 768 * 384 + 384 * 384 + BIAS_ITEMS;
  prep_kernel<<<(prep_items + 255) / 256, 256, 0, stream>>>(qw, kvw, pw, bt, wsS, biasf);

  hipFuncSetAttribute((const void*)fused_kernel,
                      hipFuncAttributeMaxDynamicSharedMemorySize, LDS_BYTES);
  fused_kernel<<<nwin, 256, LDS_BYTES, stream>>>(
      xe, xb, qb, kvb, pb,
      wsS + WQT_OFF, wsS + WKVT_OFF, wsS + WPT_OFF, biasf, out);
}

// Round 14
// 689.922 us; speedup vs baseline: 1.6754x; 1.0139x over previous
//
#include <hip/hip_runtime.h>
#include <hip/hip_bf16.h>

#define NTOK 49
#define DIM 384
#define HEADS 12
#define SCALE 0.17677669529663687f

typedef __attribute__((ext_vector_type(8))) short bf16x8;
typedef __attribute__((ext_vector_type(4))) float f32x4;

#define MFMA16(a, b, c) __builtin_amdgcn_mfma_f32_16x16x32_bf16((a), (b), (c), 0, 0, 0)

__device__ __forceinline__ short f2bf(float f) {
  __hip_bfloat16 h = __float2bfloat16(f);
  return __builtin_bit_cast(short, h);
}

// Full-K=32 fragment from two K=16 C-tile slices (same relabel on A and B -> exact).
__device__ __forceinline__ bf16x8 pack8(f32x4 a, f32x4 b) {
  bf16x8 r;
#pragma unroll
  for (int i = 0; i < 4; ++i) { r[i] = f2bf(a[i]); r[i + 4] = f2bf(b[i]); }
  return r;
}

// ws layout:
//   wqT  : short [384][384]   elem off 0        (Wq^T row-major [n][k])
//   wkvT : short [768][384]   elem off 147456   (rows 0-383 K, 384-767 V)
//   wpT  : short [384][384]   elem off 442368
//   biasf: float [12][4][4][64][4] byte off 1179648  (fragment-ordered, coalesced)
#define WQT_OFF   0
#define WKVT_OFF  147456
#define WPT_OFF   442368
#define BIAS_BYTE_OFF 1179648
#define BIAS_ITEMS (12 * 4 * 4 * 64 * 4)

__global__ void prep_kernel(const float* __restrict__ qw, const float* __restrict__ kvw,
                            const float* __restrict__ pw, const float* __restrict__ bt,
                            short* __restrict__ wsS, float* __restrict__ biasf) {
  int id = blockIdx.x * 256 + threadIdx.x;
  const int SZ1 = 384 * 384;
  const int SZ2 = 768 * 384;
  const int SZ3 = 384 * 384;
  if (id < SZ1) {
    int n = id / 384, k = id % 384;
    wsS[WQT_OFF + id] = f2bf(qw[k * 384 + n]);
  } else if (id < SZ1 + SZ2) {
    int t = id - SZ1; int n = t / 384, k = t % 384;
    wsS[WKVT_OFF + t] = f2bf(kvw[k * 768 + n]);
  } else if (id < SZ1 + SZ2 + SZ3) {
    int t = id - (SZ1 + SZ2); int n = t / 384, k = t % 384;
    wsS[WPT_OFF + t] = f2bf(pw[k * 384 + n]);
  } else if (id < SZ1 + SZ2 + SZ3 + BIAS_ITEMS) {
    int t = id - (SZ1 + SZ2 + SZ3);
    // [h][qt][tb][l][i]: lane l of fragment (qt,tb) element i
    int i  = t & 3;
    int lm = (t >> 2) & 63;
    int tb = (t >> 8) & 3;
    int qt = (t >> 10) & 3;
    int h  = t >> 12;
    int q = qt * 16 + (lm & 15);
    int k = tb * 16 + (lm >> 4) * 4 + i;
    float v = 0.0f;
    if (q < NTOK && k < NTOK) {
      int idx = ((q / 7 - k / 7) + 6) * 13 + ((q % 7 - k % 7) + 6);
      v = bt[idx * HEADS + h];
    }
    biasf[t] = v;
  }
}

// LDS (shorts). Row stride 392 shorts = 196 dw == 4 mod 32: 16-row b128 frag
// reads land 2 lanes/bank (free).
#define LDS_ELEMS 38416
#define LDS_BYTES (LDS_ELEMS * 2)   // 76832 B -> 2 blocks/CU (153664 <= 160K)

// (256,2): 2 blocks/CU, 2 waves/SIMD, 256 regs/wave (VGPR+AGPR unified).
__global__ __launch_bounds__(256, 2)
void fused_kernel(const float* __restrict__ xe, const float* __restrict__ xb,
                  const float* __restrict__ qb, const float* __restrict__ kvb,
                  const float* __restrict__ pb,
                  const short* __restrict__ wqT, const short* __restrict__ wkvT,
                  const short* __restrict__ wpT, const float* __restrict__ biasf,
                  float* __restrict__ out) {
  extern __shared__ short lds[];
  short* X    = lds;             // x_body
  short* XE   = lds + 19208;     // x_edge; becomes OALL after barrier #2
  short* OALL = XE;

  const int b   = blockIdx.x;
  const int tid = threadIdx.x;
  const int u   = tid >> 6;      // wave 0..3, owns heads 3u..3u+2
  const int l   = tid & 63;
  const int m16 = l & 15;
  const int g   = l >> 4;
  const int h0  = u * 3;

  const f32x4 zf = {0.f, 0.f, 0.f, 0.f};

  // ---- stage x_edge -> XE and x_body -> X ----
  const float* xew = xe + (size_t)b * (NTOK * DIM);
  const float* xbw = xb + (size_t)b * (NTOK * DIM);
#pragma unroll 4
  for (int i4 = tid; i4 < 2 * 4704; i4 += 256) {
    int eb = i4 < 4704;
    int e = (eb ? i4 : i4 - 4704) * 4;
    const float* src = eb ? xew : xbw;
    short* dst = eb ? XE : X;
    int r = e / DIM, c = e % DIM;
    float4 v = *(const float4*)(src + e);
    ushort4 s;
    s.x = (unsigned short)f2bf(v.x); s.y = (unsigned short)f2bf(v.y);
    s.z = (unsigned short)f2bf(v.z); s.w = (unsigned short)f2bf(v.w);
    *(ushort4*)&dst[r * 392 + c] = s;
  }
  __syncthreads();   // [#1]

  // ===== Q pass: merged 3 heads (6 weight streams, 2-deep pipeline) =========
  bf16x8 qfr[3][4];
  {
    f32x4 qc[6][4];   // t = hh*2 + dt
#pragma unroll
    for (int t = 0; t < 6; ++t)
#pragma unroll
      for (int tb = 0; tb < 4; ++tb) qc[t][tb] = zf;

    const short* wq[6];
    bf16x8 w0[6], w1[6];
#pragma unroll
    for (int t = 0; t < 6; ++t) {
      wq[t] = wqT + (size_t)((h0 + (t >> 1)) * 32 + (t & 1) * 16 + m16) * 384;
      w0[t] = *(const bf16x8*)(wq[t] + g * 8);
      w1[t] = *(const bf16x8*)(wq[t] + 32 + g * 8);
    }
#pragma unroll 1
    for (int kk = 0; kk < 12; kk += 2) {
      const int ko2 = ((kk + 2) % 12) * 32 + g * 8;   // wrap: harmless dead load
      const int ko3 = ((kk + 3) % 12) * 32 + g * 8;
      bf16x8 n0[6], n1[6];
#pragma unroll
      for (int t = 0; t < 6; ++t) n0[t] = *(const bf16x8*)(wq[t] + ko2);
#pragma unroll
      for (int t = 0; t < 6; ++t) n1[t] = *(const bf16x8*)(wq[t] + ko3);
      const int koA = kk * 32 + g * 8;
      const int koB = (kk + 1) * 32 + g * 8;
#pragma unroll
      for (int tb = 0; tb < 4; ++tb) {
        int tr = tb * 16 + m16; tr = tr < 49 ? tr : 48;
        bf16x8 xv = *(const bf16x8*)(&XE[tr * 392 + koA]);
#pragma unroll
        for (int t = 0; t < 6; ++t) qc[t][tb] = MFMA16(w0[t], xv, qc[t][tb]);
      }
#pragma unroll
      for (int tb = 0; tb < 4; ++tb) {
        int tr = tb * 16 + m16; tr = tr < 49 ? tr : 48;
        bf16x8 xv = *(const bf16x8*)(&XE[tr * 392 + koB]);
#pragma unroll
        for (int t = 0; t < 6; ++t) qc[t][tb] = MFMA16(w1[t], xv, qc[t][tb]);
      }
#pragma unroll
      for (int t = 0; t < 6; ++t) { w0[t] = n0[t]; w1[t] = n1[t]; }
    }
#pragma unroll
    for (int hh = 0; hh < 3; ++hh) {
      const int h = h0 + hh;
      float4 t0 = *(const float4*)(qb + h * 32 + g * 4);
      float4 t1 = *(const float4*)(qb + h * 32 + 16 + g * 4);
      f32x4 b0 = {t0.x, t0.y, t0.z, t0.w};
      f32x4 b1 = {t1.x, t1.y, t1.z, t1.w};
#pragma unroll
      for (int qt = 0; qt < 4; ++qt)
        qfr[hh][qt] = pack8((qc[hh * 2][qt] + b0) * SCALE, (qc[hh * 2 + 1][qt] + b1) * SCALE);
    }
  }
  __syncthreads();   // [#2] all XE reads done -> XE becomes OALL

  // == per head: merged K+V GEMM (2-deep weight + full-iter xv pipeline) ======
#pragma unroll
  for (int hh = 0; hh < 3; ++hh) {
    const int h = h0 + hh;

    f32x4 kc0[4], kc1[4], vc0[4], vc1[4];
#pragma unroll
    for (int tb = 0; tb < 4; ++tb) { kc0[tb] = zf; kc1[tb] = zf; vc0[tb] = zf; vc1[tb] = zf; }
    const short* wk0 = wkvT + (size_t)(h * 32 + m16) * 384;
    const short* wk1 = wkvT + (size_t)(h * 32 + 16 + m16) * 384;
    const short* wv0 = wkvT + (size_t)(384 + h * 32 + m16) * 384;
    const short* wv1 = wkvT + (size_t)(384 + h * 32 + 16 + m16) * 384;
    // weight slots: [k0,k1,v0,v1] x {even,odd}
    bf16x8 a0 = *(const bf16x8*)(wk0 + g * 8), a1 = *(const bf16x8*)(wk1 + g * 8);
    bf16x8 a2 = *(const bf16x8*)(wv0 + g * 8), a3 = *(const bf16x8*)(wv1 + g * 8);
    bf16x8 b0 = *(const bf16x8*)(wk0 + 32 + g * 8), b1 = *(const bf16x8*)(wk1 + 32 + g * 8);
    bf16x8 b2 = *(const bf16x8*)(wv0 + 32 + g * 8), b3 = *(const bf16x8*)(wv1 + 32 + g * 8);
    bf16x8 xA[4];
#pragma unroll
    for (int tb = 0; tb < 4; ++tb) {
      int tr = tb * 16 + m16; tr = tr < 49 ? tr : 48;
      xA[tb] = *(const bf16x8*)(&X[tr * 392 + g * 8]);
    }
#pragma unroll 1
    for (int kk = 0; kk < 12; kk += 2) {
      const int ko2 = ((kk + 2) % 12) * 32 + g * 8;   // wrap: harmless dead load
      const int ko3 = ((kk + 3) % 12) * 32 + g * 8;
      bf16x8 n0 = *(const bf16x8*)(wk0 + ko2), n1 = *(const bf16x8*)(wk1 + ko2);
      bf16x8 n2 = *(const bf16x8*)(wv0 + ko2), n3 = *(const bf16x8*)(wv1 + ko2);
      bf16x8 m0 = *(const bf16x8*)(wk0 + ko3), m1 = *(const bf16x8*)(wk1 + ko3);
      bf16x8 m2 = *(const bf16x8*)(wv0 + ko3), m3 = *(const bf16x8*)(wv1 + ko3);
      const int koB = (kk + 1) * 32 + g * 8;
      bf16x8 xB[4];
#pragma unroll
      for (int tb = 0; tb < 4; ++tb) {
        int tr = tb * 16 + m16; tr = tr < 49 ? tr : 48;
        xB[tb] = *(const bf16x8*)(&X[tr * 392 + koB]);
      }
      // compute half A (weights a*, frags xA)
#pragma unroll
      for (int tb = 0; tb < 4; ++tb) {
        kc0[tb] = MFMA16(a0, xA[tb], kc0[tb]);
        kc1[tb] = MFMA16(a1, xA[tb], kc1[tb]);
        vc0[tb] = MFMA16(xA[tb], a2, vc0[tb]);
        vc1[tb] = MFMA16(xA[tb], a3, vc1[tb]);
      }
      // prefetch next even xv (full-iter distance)
#pragma unroll
      for (int tb = 0; tb < 4; ++tb) {
        int tr = tb * 16 + m16; tr = tr < 49 ? tr : 48;
        xA[tb] = *(const bf16x8*)(&X[tr * 392 + ko2]);
      }
      // compute half B (weights b*, frags xB)
#pragma unroll
      for (int tb = 0; tb < 4; ++tb) {
        kc0[tb] = MFMA16(b0, xB[tb], kc0[tb]);
        kc1[tb] = MFMA16(b1, xB[tb], kc1[tb]);
        vc0[tb] = MFMA16(xB[tb], b2, vc0[tb]);
        vc1[tb] = MFMA16(xB[tb], b3, vc1[tb]);
      }
      a0 = n0; a1 = n1; a2 = n2; a3 = n3;
      b0 = m0; b1 = m1; b2 = m2; b3 = m3;
    }
    // ---- fold biases, pack fragments ----
    bf16x8 kfr[4], vfr[2][2];
    {
      float4 t0 = *(const float4*)(kvb + h * 32 + g * 4);
      float4 t1 = *(const float4*)(kvb + h * 32 + 16 + g * 4);
      f32x4 c0 = {t0.x, t0.y, t0.z, t0.w};
      f32x4 c1 = {t1.x, t1.y, t1.z, t1.w};
#pragma unroll
      for (int tb = 0; tb < 4; ++tb) kfr[tb] = pack8(kc0[tb] + c0, kc1[tb] + c1);
    }
    {
      float vb0 = kvb[384 + h * 32 + m16];
      float vb1 = kvb[384 + h * 32 + 16 + m16];
      f32x4 bv0 = {vb0, vb0, vb0, vb0};
      f32x4 bv1 = {vb1, vb1, vb1, vb1};
#pragma unroll
      for (int t = 0; t < 2; ++t) {
        vfr[t][0] = pack8(vc0[2 * t] + bv0, vc0[2 * t + 1] + bv0);
        vfr[t][1] = pack8(vc1[2 * t] + bv1, vc1[2 * t + 1] + bv1);
      }
    }

    // ============ attention per q-tile; O flushed immediately ============
    const float4* bfh = (const float4*)biasf + (size_t)h * 4 * 4 * 64;
#pragma unroll
    for (int qt = 0; qt < 4; ++qt) {
      const float4* bq = bfh + qt * 4 * 64;
      float4 c0 = bq[l], c1 = bq[64 + l], c2 = bq[128 + l], c3 = bq[192 + l];
      f32x4 B0 = {c0.x, c0.y, c0.z, c0.w};
      f32x4 B1 = {c1.x, c1.y, c1.z, c1.w};
      f32x4 B2 = {c2.x, c2.y, c2.z, c2.w};
      f32x4 B3 = {c3.x, c3.y, c3.z, c3.w};
      f32x4 s[4];
#pragma unroll
      for (int tb = 0; tb < 4; ++tb) s[tb] = MFMA16(kfr[tb], qfr[hh][qt], zf);

      float sv[4][4];
#pragma unroll
      for (int i = 0; i < 4; ++i) {
        sv[0][i] = s[0][i] + B0[i];
        sv[1][i] = s[1][i] + B1[i];
        sv[2][i] = s[2][i] + B2[i];
        // tb=3: k = 48 + g*4 + i -> only (g==0,i==0) is a real key
        sv[3][i] = (g == 0 && i == 0) ? s[3][0] + B3[0] : -3.0e38f;
      }
      float mx = -3.0e38f;
#pragma unroll
      for (int tb = 0; tb < 4; ++tb)
#pragma unroll
        for (int i = 0; i < 4; ++i) mx = fmaxf(mx, sv[tb][i]);
      mx = fmaxf(mx, __shfl_xor(mx, 16));
      mx = fmaxf(mx, __shfl_xor(mx, 32));
      float sum = 0.f;
#pragma unroll
      for (int tb = 0; tb < 4; ++tb)
#pragma unroll
        for (int i = 0; i < 4; ++i) {
          float e = __expf(sv[tb][i] - mx);
          sv[tb][i] = e;
          sum += e;
        }
      sum += __shfl_xor(sum, 16);
      sum += __shfl_xor(sum, 32);
      float inv = 1.0f / sum;

      bf16x8 pfr[2];
#pragma unroll
      for (int t = 0; t < 2; ++t) {
        f32x4 lo = {sv[2 * t][0] * inv, sv[2 * t][1] * inv, sv[2 * t][2] * inv, sv[2 * t][3] * inv};
        f32x4 hi = {sv[2 * t + 1][0] * inv, sv[2 * t + 1][1] * inv, sv[2 * t + 1][2] * inv, sv[2 * t + 1][3] * inv};
        pfr[t] = pack8(lo, hi);
      }
      f32x4 o0 = zf, o1 = zf;
      o0 = MFMA16(pfr[0], vfr[0][0], o0); o0 = MFMA16(pfr[1], vfr[1][0], o0);
      o1 = MFMA16(pfr[0], vfr[0][1], o1); o1 = MFMA16(pfr[1], vfr[1][1], o1);
#pragma unroll
      for (int i = 0; i < 4; ++i) {
        int r = qt * 16 + g * 4 + i;
        if (r < 49) {
          OALL[r * 392 + h * 32 + m16]      = f2bf(o0[i]);
          OALL[r * 392 + h * 32 + 16 + m16] = f2bf(o1[i]);
        }
      }
    }
  }
  __syncthreads();   // [#3] OALL complete

  // ====== out-projection: wave u owns col-tiles u*6..u*6+5 (2-deep bw, af pp)
  {
    f32x4 pacc[4][6];
#pragma unroll
    for (int qt = 0; qt < 4; ++qt)
#pragma unroll
      for (int c = 0; c < 6; ++c) pacc[qt][c] = zf;

    int rq[4];
#pragma unroll
    for (int qt = 0; qt < 4; ++qt) {
      int r = qt * 16 + m16; rq[qt] = r < 49 ? r : 48;
    }
    const short* wp[6];
    bf16x8 w0[6], w1[6];
#pragma unroll
    for (int c = 0; c < 6; ++c) {
      wp[c] = wpT + (size_t)((u * 6 + c) * 16 + m16) * 384;
      w0[c] = *(const bf16x8*)(wp[c] + g * 8);
      w1[c] = *(const bf16x8*)(wp[c] + 32 + g * 8);
    }
    bf16x8 afA[4];
#pragma unroll
    for (int qt = 0; qt < 4; ++qt) afA[qt] = *(const bf16x8*)(&OALL[rq[qt] * 392 + g * 8]);
#pragma unroll 1
    for (int kk = 0; kk < 12; kk += 2) {
      const int ko2 = ((kk + 2) % 12) * 32 + g * 8;   // wrap: harmless dead load
      const int ko3 = ((kk + 3) % 12) * 32 + g * 8;
      bf16x8 n0[6], n1[6];
#pragma unroll
      for (int c = 0; c < 6; ++c) n0[c] = *(const bf16x8*)(wp[c] + ko2);
#pragma unroll
      for (int c = 0; c < 6; ++c) n1[c] = *(const bf16x8*)(wp[c] + ko3);
      const int koB = (kk + 1) * 32 + g * 8;
      bf16x8 afB[4];
#pragma unroll
      for (int qt = 0; qt < 4; ++qt) afB[qt] = *(const bf16x8*)(&OALL[rq[qt] * 392 + koB]);
      // half A
#pragma unroll
      for (int c = 0; c < 6; ++c)
#pragma unroll
        for (int qt = 0; qt < 4; ++qt) pacc[qt][c] = MFMA16(afA[qt], w0[c], pacc[qt][c]);
      // prefetch next even af (full-iter distance)
#pragma unroll
      for (int qt = 0; qt < 4; ++qt) afA[qt] = *(const bf16x8*)(&OALL[rq[qt] * 392 + ko2]);
      // half B
#pragma unroll
      for (int c = 0; c < 6; ++c)
#pragma unroll
        for (int qt = 0; qt < 4; ++qt) pacc[qt][c] = MFMA16(afB[qt], w1[c], pacc[qt][c]);
#pragma unroll
      for (int c = 0; c < 6; ++c) { w0[c] = n0[c]; w1[c] = n1[c]; }
    }
    float* outw = out + (size_t)b * (NTOK * DIM);
#pragma unroll
    for (int c = 0; c < 6; ++c) {
      int col = (u * 6 + c) * 16 + m16;
      float pbv = pb[col];
#pragma unroll
      for (int qt = 0; qt < 4; ++qt)
#pragma unroll
        for (int i = 0; i < 4; ++i) {
          int r = qt * 16 + g * 4 + i;
          if (r < 49) outw[r * DIM + col] = pacc[qt][c][i] + pbv;
        }
    }
  }
}

extern "C" void kernel_launch(void* const* d_in, const int* in_sizes, int n_in,
                              void* d_out, int out_size, void* d_ws, size_t ws_size,
                              hipStream_t stream) {
  const float* xe  = (const float*)d_in[0];
  const float* xb  = (const float*)d_in[1];
  const float* qw  = (const float*)d_in[2];
  const float* qb  = (const float*)d_in[3];
  const float* kvw = (const float*)d_in[4];
  const float* kvb = (const float*)d_in[5];
  const float* pw  = (const float*)d_in[6];
  const float* pb  = (const float*)d_in[7];
  const float* bt  = (const float*)d_in[8];
  float* out = (float*)d_out;
  short* wsS = (short*)d_ws;
  float* biasf = (float*)((char*)d_ws + BIAS_BYTE_OFF);

  const int nwin = in_sizes[0] / (NTOK * DIM);

  const int prep_items = 384 * 384 + 768 * 384 + 384 * 384 + BIAS_ITEMS;
  prep_kernel<<<(prep_items + 255) / 256, 256, 0, stream>>>(qw, kvw, pw, bt, wsS, biasf);

  hipFuncSetAttribute((const void*)fused_kernel,
                      hipFuncAttributeMaxDynamicSharedMemorySize, LDS_BYTES);
  fused_kernel<<<nwin, 256, LDS_BYTES, stream>>>(
      xe, xb, qb, kvb, pb,
      wsS + WQT_OFF, wsS + WKVT_OFF, wsS + WPT_OFF, biasf, out);
}